// Round 10
// baseline (350.632 us; speedup 1.0000x reference)
//
#include <hip/hip_runtime.h>

#define BATCH 8
#define CCH 256
#define NPOS 4096
#define LOG2E 1.4426950408889634f

typedef __bf16 bf16x8 __attribute__((ext_vector_type(8)));
typedef float f32x4 __attribute__((ext_vector_type(4)));
typedef int i32x4 __attribute__((ext_vector_type(4)));
typedef int i32x2 __attribute__((ext_vector_type(2)));

typedef const __attribute__((address_space(1))) void GAS;
typedef __attribute__((address_space(3))) void LAS;

#define CFENCE() __asm__ volatile("" ::: "memory")
// vmcnt(8), lgkmcnt no-wait(15), expcnt no-wait(7): (15<<8)|(7<<4)|8
#define WAIT_VM8()  do { CFENCE(); __builtin_amdgcn_s_waitcnt(0x0F78); CFENCE(); } while (0)
// lgkmcnt(0), vmcnt no-wait(63: low4=15,hi2=3), expcnt no-wait
#define WAIT_LGKM0() do { CFENCE(); __builtin_amdgcn_s_waitcnt(0xC07F); CFENCE(); } while (0)
#define BAR_RAW() do { CFENCE(); __builtin_amdgcn_s_barrier(); CFENCE(); } while (0)

__device__ __forceinline__ unsigned short f2bf(float f) {
  unsigned u = __builtin_bit_cast(unsigned, f);
  u += 0x7fffu + ((u >> 16) & 1u);
  return (unsigned short)(u >> 16);
}

__device__ __forceinline__ bf16x8 ld_bf8(const unsigned short* p) {
  i32x4 t = *reinterpret_cast<const i32x4*>(p);
  return __builtin_bit_cast(bf16x8, t);
}

__device__ __forceinline__ float fexp2(float x) {
#if __has_builtin(__builtin_amdgcn_exp2f)
  return __builtin_amdgcn_exp2f(x);
#else
  return __builtin_exp2f(x);
#endif
}

// packed f32x2 -> bf16x2 (RNE), one VALU op
__device__ __forceinline__ unsigned cvtpk(float lo, float hi) {
  unsigned r;
  asm("v_cvt_pk_bf16_f32 %0, %1, %2" : "=v"(r) : "v"(lo), "v"(hi));
  return r;
}

// ---------------------------------------------------------------- kernel 1
__global__ void cvt_kernel(const float* __restrict__ Wq,
                           const float* __restrict__ Wk,
                           const float* __restrict__ Wv,
                           unsigned short* __restrict__ dst)
{
  const int idx = blockIdx.x * 256 + threadIdx.x;   // 0..196607
  const float* src = (idx < 65536) ? Wq : ((idx < 131072) ? Wk : Wv);
  dst[idx] = f2bf(src[idx & 65535]);
}

// ---------------------------------------------------------------- kernel 2
// Single pass per (b, pos-tile): x staged once (coalesced), 3 selectors x
// 4 o-strips from register-resident W. q pre-scaled by log2(e).
__global__ __launch_bounds__(256, 3)
void qkv_kernel(const float* __restrict__ x,
                const unsigned short* __restrict__ Wall,
                const float* __restrict__ bq,
                const float* __restrict__ bk,
                const float* __restrict__ bv,
                unsigned short* __restrict__ qT,
                unsigned short* __restrict__ kT,
                unsigned short* __restrict__ vG)
{
  __shared__ __align__(16) unsigned short xT[64 * 264];   // 33792 B
  __shared__ __align__(16) unsigned short tbuf[64 * 72];  //  9216 B

  const int b   = blockIdx.x;
  const int i0  = blockIdx.y * 64;
  const int tid = threadIdx.x;
  const int w   = tid >> 6;
  const int l   = tid & 63;
  const int n   = l & 15;
  const int q4  = l >> 4;

  {
    const int li = tid & 15;
    const int cg = tid >> 4;
#pragma unroll
    for (int it = 0; it < 16; ++it) {
      const int c = it * 16 + cg;
      f32x4 f = *reinterpret_cast<const f32x4*>(x + ((size_t)b * CCH + c) * NPOS + i0 + li * 4);
#pragma unroll
      for (int e = 0; e < 4; ++e) xT[(li * 4 + e) * 264 + c] = f2bf(f[e]);
    }
  }
  __syncthreads();

  const size_t qbase = (size_t)b * NPOS * CCH;
  bool first = true;

  for (int s = 0; s < 3; ++s) {
    const float* bias = (s == 0) ? bq : (s == 1) ? bk : bv;
    for (int op = 0; op < 4; ++op) {
      const int obase = op * 64;

      const unsigned short* Wp = Wall + s * 65536 + (size_t)(obase + w * 16 + n) * CCH + q4 * 8;
      bf16x8 wfr[8];
#pragma unroll
      for (int kk = 0; kk < 8; ++kk) wfr[kk] = ld_bf8(Wp + kk * 32);

      float bo[4];
#pragma unroll
      for (int r = 0; r < 4; ++r) bo[r] = bias[obase + w * 16 + q4 * 4 + r];

      f32x4 acc[4];
#pragma unroll
      for (int pt = 0; pt < 4; ++pt) {
        acc[pt] = {0.f, 0.f, 0.f, 0.f};
#pragma unroll
        for (int kk = 0; kk < 8; ++kk) {
          bf16x8 bfr = ld_bf8(&xT[(pt * 16 + n) * 264 + kk * 32 + q4 * 8]);
          acc[pt] = __builtin_amdgcn_mfma_f32_16x16x32_bf16(wfr[kk], bfr, acc[pt], 0, 0, 0);
        }
      }

      if (!first) __syncthreads();
      first = false;
      if (s < 2) {
        const float sc = (s == 0) ? LOG2E : 1.0f;
#pragma unroll
        for (int pt = 0; pt < 4; ++pt)
#pragma unroll
          for (int r = 0; r < 4; ++r)
            tbuf[(pt * 16 + n) * 72 + w * 16 + q4 * 4 + r] = f2bf((acc[pt][r] + bo[r]) * sc);
      } else {
#pragma unroll
        for (int pt = 0; pt < 4; ++pt)
#pragma unroll
          for (int r = 0; r < 4; ++r)
            tbuf[(w * 16 + q4 * 4 + r) * 72 + pt * 16 + n] = f2bf(acc[pt][r] + bo[r]);
      }
      __syncthreads();

      if (s < 2) {
        unsigned short* dst = (s == 0 ? qT : kT) + qbase;
#pragma unroll
        for (int it2 = 0; it2 < 2; ++it2) {
          const int idx = it2 * 256 + tid;
          const int pos = idx >> 3, ow = (idx & 7) * 8;
          i32x4 d = *reinterpret_cast<const i32x4*>(&tbuf[pos * 72 + ow]);
          *reinterpret_cast<i32x4*>(&dst[(size_t)(i0 + pos) * CCH + obase + ow]) = d;
        }
      } else {
#pragma unroll
        for (int it2 = 0; it2 < 2; ++it2) {
          const int idx = it2 * 256 + tid;
          const int o = idx >> 3, pw2 = (idx & 7) * 8;
          i32x4 d = *reinterpret_cast<const i32x4*>(&tbuf[o * 72 + pw2]);
          *reinterpret_cast<i32x4*>(&vG[qbase + (size_t)(obase + o) * NPOS + i0 + pw2]) = d;
        }
      }
    }
  }
}

// ---------------------------------------------------------------- kernel 3
// Flash attention = r9 + QK^T wave split by (i-pair, j-half):
//  - wave (ip,jh) computes S^T for j in [jh*32,+32) x i in [ip*32,+32):
//    each K A-frag reused for TWO Q B-frags -> K LDS reads halve
//    (16 b128/wave/iter), MFMA count unchanged (32).
//  - Q register set doubles (afr[2][8], +32 regs); amdgpu_waves_per_eu(2,2)
//    budgets 256 regs/wave at the SAME occupancy we already run (2 blk/CU).
//  - row sum/max now cross the wave pair via sstat LDS (piggybacks on the
//    existing P barrier; lagging-max keeps it off the critical path).
//  - PV / V-loads / O / pbuf layout / DMA / barriers: identical to r9.
__global__ __launch_bounds__(256) __attribute__((amdgpu_waves_per_eu(2, 2)))
void attn_kernel(const unsigned short* __restrict__ qT,
                 const unsigned short* __restrict__ kT,
                 const unsigned short* __restrict__ vG,
                 const float* __restrict__ x,
                 const float* __restrict__ gamma,
                 float* __restrict__ out)
{
  __shared__ __align__(16) unsigned short kbuf[2][64 * 256];  // 2 x 32768 B, swizzled
  __shared__ __align__(16) unsigned short pbuf[64 * 64];      //  8192 B, swizzled
  __shared__ float stat_lds[64];                              //  alpha / final scale
  __shared__ float sstat[2][2][64];                           //  [jh][0=sum,1=max][i]

  const int b   = blockIdx.x;
  const int i0  = blockIdx.y * 64;
  const int tid = threadIdx.x;
  const int w   = tid >> 6;
  const int l   = tid & 63;
  const int n   = l & 15;
  const int q4  = l >> 4;
  const int nsw = n & 7;
  const int ip  = w >> 1;    // i-pair: i-groups {ip*2, ip*2+1}
  const int jh  = w & 1;     // j-half

  const unsigned short* qTb = qT + (size_t)b * NPOS * CCH;
  const unsigned short* kTb = kT + (size_t)b * NPOS * CCH;
  const unsigned short* vb  = vG + (size_t)b * NPOS * CCH;

  // Q fragments register-resident, TWO i-groups (pre-scaled by log2e).
  // afr[ig][kk]: lane holds Q[i = i0 + (ip*2+ig)*16 + n][ch = kk*32 + q4*8 + e]
  bf16x8 afr[2][8];
#pragma unroll
  for (int ig = 0; ig < 2; ++ig) {
    const unsigned short* qrow = qTb + (size_t)(i0 + (ip * 2 + ig) * 16 + n) * CCH + q4 * 8;
#pragma unroll
    for (int kk = 0; kk < 8; ++kk)
      afr[ig][kk] = ld_bf8(qrow + kk * 32);
  }

  // stage K[0]: wave issues 8 DMA loads, instruction t covers local rows 2t,2t+1.
  // LDS granule (j,gp) holds logical granule g = gp ^ (j&7)  (bank-spread swizzle).
  {
#pragma unroll
    for (int it = 0; it < 8; ++it) {
      const int t = w * 8 + it;
      const int j = 2 * t + (l >> 5);
      const int gp = l & 31;
      const int g  = gp ^ (j & 7);
      const unsigned short* src = kTb + (size_t)j * CCH + g * 8;
      unsigned short* dst = &kbuf[0][t * 512];    // wave-uniform base
      __builtin_amdgcn_global_load_lds((GAS*)src, (LAS*)dst, 16, 0, 0);
    }
  }

  f32x4 O[16];   // [ct*4+it]: c in [w*64+ct*16,+16), i in [it*16,+16)  (unchanged)
#pragma unroll
  for (int t = 0; t < 16; ++t) O[t] = {0.f, 0.f, 0.f, 0.f};
  float mcur[2] = {64.f, 64.f};   // lagging exp2-domain max per i-group
  float lrow[2] = {0.f, 0.f};
  float acarry[2] = {1.0f, 1.0f};

  for (int jt = 0; jt < 64; ++jt) {
    const int j0 = jt * 64;
    const unsigned short* kb = kbuf[jt & 1];

    // prefetch V[jt] into registers (always the 8 NEWEST vmem ops) — unchanged
    i32x4 vreg[8];
#pragma unroll
    for (int ct = 0; ct < 4; ++ct) {
      const unsigned short* vp = vb + (size_t)(w * 64 + ct * 16 + n) * NPOS + j0 + q4 * 8;
      vreg[ct * 2]     = *reinterpret_cast<const i32x4*>(vp);
      vreg[ct * 2 + 1] = *reinterpret_cast<const i32x4*>(vp + 32);
    }

    WAIT_VM8();     // drain everything older than V[jt] => K[jt] DMA complete
    BAR_RAW();      // all waves' K[jt] in LDS; pbuf/stat free (readers done pre-barrier)

    // S^T = K * Q: wave (ip,jh) covers j [jh*32,+32) x i [ip*32,+32).
    // A-frag (K) loaded once, used for both i-groups.
    f32x4 sacc[2][2];   // [nt2][ig]
#pragma unroll
    for (int nt2 = 0; nt2 < 2; ++nt2)
#pragma unroll
      for (int ig = 0; ig < 2; ++ig) sacc[nt2][ig] = {0.f, 0.f, 0.f, 0.f};
    __builtin_amdgcn_s_setprio(1);
#pragma unroll
    for (int nt2 = 0; nt2 < 2; ++nt2) {
      const unsigned short* krow = kb + (jh * 32 + nt2 * 16 + n) * 256;
#pragma unroll
      for (int kk = 0; kk < 8; ++kk) {
        const int gp = (kk * 4 + q4) ^ nsw;
        bf16x8 kfr = ld_bf8(krow + gp * 8);
        sacc[nt2][0] = __builtin_amdgcn_mfma_f32_16x16x32_bf16(kfr, afr[0][kk], sacc[nt2][0], 0, 0, 0);
        sacc[nt2][1] = __builtin_amdgcn_mfma_f32_16x16x32_bf16(kfr, afr[1][kk], sacc[nt2][1], 0, 0, 0);
      }
    }
    __builtin_amdgcn_s_setprio(0);

    // per-ig: in-lane max tree (8 j) + exp2 lagging scale + sum
    float tml[2], s_[2];
#pragma unroll
    for (int ig = 0; ig < 2; ++ig) {
      float a0 = fmaxf(fmaxf(sacc[0][ig][0], sacc[0][ig][1]), fmaxf(sacc[0][ig][2], sacc[0][ig][3]));
      float a1 = fmaxf(fmaxf(sacc[1][ig][0], sacc[1][ig][1]), fmaxf(sacc[1][ig][2], sacc[1][ig][3]));
      tml[ig] = fmaxf(a0, a1);
      float s = 0.f;
#pragma unroll
      for (int nt2 = 0; nt2 < 2; ++nt2)
#pragma unroll
        for (int r = 0; r < 4; ++r) {
          const float p = fexp2(sacc[nt2][ig][r] - mcur[ig]);
          sacc[nt2][ig][r] = p;
          s += p;
        }
      s_[ig] = s;
    }

    // P -> pbuf: row i = (ip*2+ig)*16+n, j-slot jh*32 + nt2*16 + q4*4 + r.
    // logical granule g = jh*4 + nt2*2 + (q4>>1); phys = g ^ (row&7) = g ^ nsw.
#pragma unroll
    for (int ig = 0; ig < 2; ++ig) {
      const int rowb = ((ip * 2 + ig) * 16 + n) * 64;
#pragma unroll
      for (int nt2 = 0; nt2 < 2; ++nt2) {
        const unsigned lo = cvtpk(sacc[nt2][ig][0], sacc[nt2][ig][1]);
        const unsigned hi = cvtpk(sacc[nt2][ig][2], sacc[nt2][ig][3]);
        const int pg = (jh * 4 + nt2 * 2 + (q4 >> 1)) ^ nsw;
        i32x2 dv = { (int)lo, (int)hi };
        *reinterpret_cast<i32x2*>(&pbuf[rowb + pg * 8 + (q4 & 1) * 4]) = dv;
      }
    }

    // own-half reductions across q4 (off the exp critical path)
#pragma unroll
    for (int ig = 0; ig < 2; ++ig) {
      s_[ig] += __shfl_xor(s_[ig], 16);
      s_[ig] += __shfl_xor(s_[ig], 32);
      tml[ig] = fmaxf(tml[ig], __shfl_xor(tml[ig], 16));
      tml[ig] = fmaxf(tml[ig], __shfl_xor(tml[ig], 32));
    }

    // half-stats + alpha to LDS (consumed after the P barrier)
    if (q4 == 0) {
#pragma unroll
      for (int ig = 0; ig < 2; ++ig) {
        const int irow = (ip * 2 + ig) * 16 + n;
        sstat[jh][0][irow] = s_[ig];
        sstat[jh][1][irow] = tml[ig];
        if (jh == 0) stat_lds[irow] = acarry[ig];   // rescale decided last iter
      }
    }

    // prefetch K[jt+1] DMA into other buffer (UNCONDITIONAL, wrapped) — unchanged
    {
      const int j0n = ((jt + 1) & 63) * 64;
      unsigned short* bufn = kbuf[(jt + 1) & 1];
#pragma unroll
      for (int it = 0; it < 8; ++it) {
        const int t = w * 8 + it;
        const int j = 2 * t + (l >> 5);
        const int gp = l & 31;
        const int g  = gp ^ (j & 7);
        const unsigned short* src = kTb + (size_t)(j0n + j) * CCH + g * 8;
        unsigned short* dst = &bufn[t * 512];
        __builtin_amdgcn_global_load_lds((GAS*)src, (LAS*)dst, 16, 0, 0);
      }
    }

    WAIT_LGKM0();   // my P/stat writes landed
    BAR_RAW();      // P + stats + alpha visible; K' DMA still in flight

    // partner-half stats (broadcast reads)
    float sp[2], mp[2];
#pragma unroll
    for (int ig = 0; ig < 2; ++ig) {
      const int irow = (ip * 2 + ig) * 16 + n;
      sp[ig] = sstat[jh ^ 1][0][irow];
      mp[ig] = sstat[jh ^ 1][1][irow];
    }

    // rescale O by alpha[i] — skipped when no row updated last iter (unchanged)
    {
      const float al0 = stat_lds[n];
      const float al1 = stat_lds[16 + n];
      const float al2 = stat_lds[32 + n];
      const float al3 = stat_lds[48 + n];
      if (al0 + al1 + al2 + al3 != 4.0f) {
        const float als[4] = { al0, al1, al2, al3 };
#pragma unroll
        for (int it = 0; it < 4; ++it) {
          const float al = als[it];
#pragma unroll
          for (int ct = 0; ct < 4; ++ct) {
            f32x4& o = O[ct * 4 + it];
            o[0] *= al; o[1] *= al; o[2] *= al; o[3] *= al;
          }
        }
      }
    }

    // PV: V from registers, P from swizzled LDS — unchanged
    bf16x8 pf[8];
#pragma unroll
    for (int it = 0; it < 4; ++it) {
      const int rowb = (it * 16 + n) * 64;
      pf[it * 2 + 0] = ld_bf8(&pbuf[rowb + ((q4 ^ nsw) << 3)]);
      pf[it * 2 + 1] = ld_bf8(&pbuf[rowb + (((4 + q4) ^ nsw) << 3)]);
    }
    __builtin_amdgcn_s_setprio(1);
#pragma unroll
    for (int ct = 0; ct < 4; ++ct) {
      bf16x8 vf0 = __builtin_bit_cast(bf16x8, vreg[ct * 2]);
      bf16x8 vf1 = __builtin_bit_cast(bf16x8, vreg[ct * 2 + 1]);
#pragma unroll
      for (int it = 0; it < 4; ++it) {
        O[ct * 4 + it] = __builtin_amdgcn_mfma_f32_16x16x32_bf16(vf0, pf[it * 2 + 0], O[ct * 4 + it], 0, 0, 0);
        O[ct * 4 + it] = __builtin_amdgcn_mfma_f32_16x16x32_bf16(vf1, pf[it * 2 + 1], O[ct * 4 + it], 0, 0, 0);
      }
    }
    __builtin_amdgcn_s_setprio(0);

    // combine halves; deferred max update (rare, threshold 8)
    const float tm0 = fmaxf(tml[0], mp[0]);
    const float tm1 = fmaxf(tml[1], mp[1]);
    lrow[0] += s_[0] + sp[0];
    lrow[1] += s_[1] + sp[1];
    const int upd0 = tm0 > mcur[0] + 8.f;
    const int upd1 = tm1 > mcur[1] + 8.f;
    if (__any(upd0 | upd1)) {
      {
        const float mn = upd0 ? tm0 : mcur[0];
        const float al = fexp2(mcur[0] - mn);
        mcur[0] = mn; lrow[0] *= al; acarry[0] = al;
      }
      {
        const float mn = upd1 ? tm1 : mcur[1];
        const float al = fexp2(mcur[1] - mn);
        mcur[1] = mn; lrow[1] *= al; acarry[1] = al;
      }
    } else {
      acarry[0] = 1.0f; acarry[1] = 1.0f;
    }
  }

  // epilogue: out = x + g*(acarry*O)/lrow — acarry folds the final pending
  // rescale (r8 lesson). Written once per i by the jh==0 wave.
  __syncthreads();
  if (q4 == 0 && jh == 0) {
#pragma unroll
    for (int ig = 0; ig < 2; ++ig)
      stat_lds[(ip * 2 + ig) * 16 + n] = acarry[ig] / lrow[ig];
  }
  __syncthreads();

  const float g = gamma[0];
#pragma unroll
  for (int it = 0; it < 4; ++it) {
    const float sc = g * stat_lds[it * 16 + n];
    const int ipos = i0 + it * 16 + n;
#pragma unroll
    for (int ct = 0; ct < 4; ++ct) {
#pragma unroll
      for (int r = 0; r < 4; ++r) {
        const int c = w * 64 + ct * 16 + q4 * 4 + r;
        const size_t idx = ((size_t)(b * CCH + c)) * NPOS + ipos;
        out[idx] = x[idx] + sc * O[ct * 4 + it][r];
      }
    }
  }
}

// ---------------------------------------------------------------- launch
extern "C" void kernel_launch(void* const* d_in, const int* in_sizes, int n_in,
                              void* d_out, int out_size, void* d_ws, size_t ws_size,
                              hipStream_t stream)
{
  const float* x     = (const float*)d_in[0];
  const float* Wq    = (const float*)d_in[1];
  const float* bq    = (const float*)d_in[2];
  const float* Wk    = (const float*)d_in[3];
  const float* bk    = (const float*)d_in[4];
  const float* Wv    = (const float*)d_in[5];
  const float* bv    = (const float*)d_in[6];
  const float* gamma = (const float*)d_in[7];
  float* out = (float*)d_out;

  unsigned short* ws   = (unsigned short*)d_ws;
  unsigned short* Wall = ws;                                  // 3 x 65536 bf16
  unsigned short* qT   = ws + 196608;                         // (B,N,C) bf16, pre-scaled log2e
  unsigned short* kT   = qT + (size_t)BATCH * NPOS * CCH;     // (B,N,C) bf16
  unsigned short* vG   = kT + (size_t)BATCH * NPOS * CCH;     // (B,C,N) bf16

  cvt_kernel<<<768, 256, 0, stream>>>(Wq, Wk, Wv, Wall);
  qkv_kernel<<<dim3(8, 64), 256, 0, stream>>>(x, Wall, bq, bk, bv, qT, kT, vG);
  attn_kernel<<<dim3(8, 64), 256, 0, stream>>>(qT, kT, vG, x, gamma, out);
}

// Round 11
// 292.029 us; speedup vs baseline: 1.2007x; 1.2007x over previous
//
#include <hip/hip_runtime.h>

#define BATCH 8
#define CCH 256
#define NPOS 4096
#define LOG2E 1.4426950408889634f

typedef __bf16 bf16x8 __attribute__((ext_vector_type(8)));
typedef float f32x4 __attribute__((ext_vector_type(4)));
typedef int i32x4 __attribute__((ext_vector_type(4)));
typedef int i32x2 __attribute__((ext_vector_type(2)));

typedef const __attribute__((address_space(1))) void GAS;
typedef __attribute__((address_space(3))) void LAS;

#define CFENCE() __asm__ volatile("" ::: "memory")
// vmcnt(8), lgkmcnt no-wait(15), expcnt no-wait(7): (15<<8)|(7<<4)|8
#define WAIT_VM8()  do { CFENCE(); __builtin_amdgcn_s_waitcnt(0x0F78); CFENCE(); } while (0)
// lgkmcnt(0), vmcnt no-wait(63: low4=15,hi2=3), expcnt no-wait
#define WAIT_LGKM0() do { CFENCE(); __builtin_amdgcn_s_waitcnt(0xC07F); CFENCE(); } while (0)
#define BAR_RAW() do { CFENCE(); __builtin_amdgcn_s_barrier(); CFENCE(); } while (0)

__device__ __forceinline__ unsigned short f2bf(float f) {
  unsigned u = __builtin_bit_cast(unsigned, f);
  u += 0x7fffu + ((u >> 16) & 1u);
  return (unsigned short)(u >> 16);
}

__device__ __forceinline__ bf16x8 ld_bf8(const unsigned short* p) {
  i32x4 t = *reinterpret_cast<const i32x4*>(p);
  return __builtin_bit_cast(bf16x8, t);
}

__device__ __forceinline__ float fexp2(float x) {
#if __has_builtin(__builtin_amdgcn_exp2f)
  return __builtin_amdgcn_exp2f(x);
#else
  return __builtin_exp2f(x);
#endif
}

// packed f32x2 -> bf16x2 (RNE), one VALU op
__device__ __forceinline__ unsigned cvtpk(float lo, float hi) {
  unsigned r;
  asm("v_cvt_pk_bf16_f32 %0, %1, %2" : "=v"(r) : "v"(lo), "v"(hi));
  return r;
}

// ---------------------------------------------------------------- kernel 1
__global__ void cvt_kernel(const float* __restrict__ Wq,
                           const float* __restrict__ Wk,
                           const float* __restrict__ Wv,
                           unsigned short* __restrict__ dst)
{
  const int idx = blockIdx.x * 256 + threadIdx.x;   // 0..196607
  const float* src = (idx < 65536) ? Wq : ((idx < 131072) ? Wk : Wv);
  dst[idx] = f2bf(src[idx & 65535]);
}

// ---------------------------------------------------------------- kernel 2
// 12 fully-unrolled phases (s-major, 4 o-strips each), restructured:
//  - W + bias for phase p+1 prefetched at top of phase p (latency hidden
//    under phase p's MFMAs; was a ~500cy serial stall per phase)
//  - tbuf double-buffered: ONE __syncthreads per phase (was two);
//    stores from tbuf[p&1] overlap phase p+1's MFMAs
//  - LDS 33.8 + 18.4 = 52.2 KB -> still 3 blocks/CU
__global__ __launch_bounds__(256, 3)
void qkv_kernel(const float* __restrict__ x,
                const unsigned short* __restrict__ Wall,
                const float* __restrict__ bq,
                const float* __restrict__ bk,
                const float* __restrict__ bv,
                unsigned short* __restrict__ qT,
                unsigned short* __restrict__ kT,
                unsigned short* __restrict__ vG)
{
  __shared__ __align__(16) unsigned short xT[64 * 264];      // 33792 B
  __shared__ __align__(16) unsigned short tbuf[2][64 * 72];  // 18432 B

  const int b   = blockIdx.x;
  const int i0  = blockIdx.y * 64;
  const int tid = threadIdx.x;
  const int w   = tid >> 6;
  const int l   = tid & 63;
  const int n   = l & 15;
  const int q4  = l >> 4;

  // stage x tile, coalesced: 16 lanes read one contiguous 256B channel row
  {
    const int li = tid & 15;
    const int cg = tid >> 4;
#pragma unroll
    for (int it = 0; it < 16; ++it) {
      const int c = it * 16 + cg;
      f32x4 f = *reinterpret_cast<const f32x4*>(x + ((size_t)b * CCH + c) * NPOS + i0 + li * 4);
#pragma unroll
      for (int e = 0; e < 4; ++e) xT[(li * 4 + e) * 264 + c] = f2bf(f[e]);
    }
  }
  __syncthreads();

  const size_t qbase = (size_t)b * NPOS * CCH;
  const float* const biases[3] = { bq, bk, bv };

  // prefetch phase 0 W strip + bias
  bf16x8 wcur[8];
  float bcur[4];
  {
    const unsigned short* Wp = Wall + (size_t)(w * 16 + n) * CCH + q4 * 8;
#pragma unroll
    for (int kk = 0; kk < 8; ++kk) wcur[kk] = ld_bf8(Wp + kk * 32);
#pragma unroll
    for (int r = 0; r < 4; ++r) bcur[r] = bq[w * 16 + q4 * 4 + r];
  }

#pragma unroll
  for (int ph = 0; ph < 12; ++ph) {
    const int s = ph >> 2, op = ph & 3, obase = op * 64;

    // prefetch next phase's W + bias (covered by this phase's MFMAs)
    bf16x8 wnxt[8];
    float bnxt[4];
    if (ph < 11) {
      const int s2 = (ph + 1) >> 2, op2 = (ph + 1) & 3;
      const unsigned short* Wp =
          Wall + s2 * 65536 + (size_t)(op2 * 64 + w * 16 + n) * CCH + q4 * 8;
#pragma unroll
      for (int kk = 0; kk < 8; ++kk) wnxt[kk] = ld_bf8(Wp + kk * 32);
      const float* b2 = biases[s2];
#pragma unroll
      for (int r = 0; r < 4; ++r) bnxt[r] = b2[op2 * 64 + w * 16 + q4 * 4 + r];
    }

    f32x4 acc[4];
#pragma unroll
    for (int pt = 0; pt < 4; ++pt) {
      acc[pt] = {0.f, 0.f, 0.f, 0.f};
#pragma unroll
      for (int kk = 0; kk < 8; ++kk) {
        bf16x8 bfr = ld_bf8(&xT[(pt * 16 + n) * 264 + kk * 32 + q4 * 8]);
        acc[pt] = __builtin_amdgcn_mfma_f32_16x16x32_bf16(wcur[kk], bfr, acc[pt], 0, 0, 0);
      }
    }

    // write tbuf[ph&1]  (D layout: col = lane&15 = pos, row = o-local)
    unsigned short* tb = tbuf[ph & 1];
    if (s < 2) {
      const float sc = (s == 0) ? LOG2E : 1.0f;
#pragma unroll
      for (int pt = 0; pt < 4; ++pt)
#pragma unroll
        for (int r = 0; r < 4; ++r)
          tb[(pt * 16 + n) * 72 + w * 16 + q4 * 4 + r] = f2bf((acc[pt][r] + bcur[r]) * sc);
    } else {
#pragma unroll
      for (int pt = 0; pt < 4; ++pt)
#pragma unroll
        for (int r = 0; r < 4; ++r)
          tb[(w * 16 + q4 * 4 + r) * 72 + pt * 16 + n] = f2bf(acc[pt][r] + bcur[r]);
    }
    __syncthreads();   // tb visible; previous parity's readers also done

    // stores from tbuf[ph&1] (overlap next phase's prefetch+MFMAs)
    if (s < 2) {
      unsigned short* dst = (s == 0 ? qT : kT) + qbase;
#pragma unroll
      for (int it2 = 0; it2 < 2; ++it2) {
        const int idx = it2 * 256 + tid;
        const int pos = idx >> 3, ow = (idx & 7) * 8;
        i32x4 d = *reinterpret_cast<const i32x4*>(&tb[pos * 72 + ow]);
        *reinterpret_cast<i32x4*>(&dst[(size_t)(i0 + pos) * CCH + obase + ow]) = d;
      }
    } else {
#pragma unroll
      for (int it2 = 0; it2 < 2; ++it2) {
        const int idx = it2 * 256 + tid;
        const int o = idx >> 3, pw2 = (idx & 7) * 8;
        i32x4 d = *reinterpret_cast<const i32x4*>(&tb[o * 72 + pw2]);
        *reinterpret_cast<i32x4*>(&vG[qbase + (size_t)(obase + o) * NPOS + i0 + pw2]) = d;
      }
    }

    if (ph < 11) {
#pragma unroll
      for (int kk = 0; kk < 8; ++kk) wcur[kk] = wnxt[kk];
#pragma unroll
      for (int r = 0; r < 4; ++r) bcur[r] = bnxt[r];
    }
  }
}

// ---------------------------------------------------------------- kernel 3
// Flash attention — byte-identical to the r9 kernel (verified 208 µs,
// absmax 0.0156): S^T operand swap, lagging-max softmax (epilogue folds the
// final pending rescale), rescale-skip, setprio, swizzled K/P LDS, K DMA
// double-buffer, V per-lane global b128.
__global__ __launch_bounds__(256, 2)
void attn_kernel(const unsigned short* __restrict__ qT,
                 const unsigned short* __restrict__ kT,
                 const unsigned short* __restrict__ vG,
                 const float* __restrict__ x,
                 const float* __restrict__ gamma,
                 float* __restrict__ out)
{
  __shared__ __align__(16) unsigned short kbuf[2][64 * 256];  // 2 x 32768 B, swizzled
  __shared__ __align__(16) unsigned short pbuf[64 * 64];      //  8192 B, swizzled
  __shared__ float stat_lds[64];

  const int b   = blockIdx.x;
  const int i0  = blockIdx.y * 64;
  const int tid = threadIdx.x;
  const int w   = tid >> 6;
  const int l   = tid & 63;
  const int n   = l & 15;
  const int q4  = l >> 4;
  const int nsw = n & 7;

  const unsigned short* qTb = qT + (size_t)b * NPOS * CCH;
  const unsigned short* kTb = kT + (size_t)b * NPOS * CCH;
  const unsigned short* vb  = vG + (size_t)b * NPOS * CCH;

  // Q fragments register-resident (pre-scaled by log2e). Used as B operand:
  // lane holds Q[i = i0 + w*16 + n][ch = kk*32 + q4*8 + e]
  bf16x8 afr[8];
  {
    const unsigned short* qrow = qTb + (size_t)(i0 + w * 16 + n) * CCH + q4 * 8;
#pragma unroll
    for (int kk = 0; kk < 8; ++kk)
      afr[kk] = ld_bf8(qrow + kk * 32);
  }

  // stage K[0]: wave issues 8 DMA loads, instruction t covers local rows 2t,2t+1.
  // LDS granule (j,gp) holds logical granule g = gp ^ (j&7)  (bank-spread swizzle).
  {
#pragma unroll
    for (int it = 0; it < 8; ++it) {
      const int t = w * 8 + it;
      const int j = 2 * t + (l >> 5);
      const int gp = l & 31;
      const int g  = gp ^ (j & 7);
      const unsigned short* src = kTb + (size_t)j * CCH + g * 8;
      unsigned short* dst = &kbuf[0][t * 512];    // wave-uniform base
      __builtin_amdgcn_global_load_lds((GAS*)src, (LAS*)dst, 16, 0, 0);
    }
  }

  f32x4 O[16];   // [ct*4+it]: c in [w*64+ct*16,+16), i in [it*16,+16)
#pragma unroll
  for (int t = 0; t < 16; ++t) O[t] = {0.f, 0.f, 0.f, 0.f};
  float mcur = 64.f;    // lagging exp2-domain max for i = i0 + w*16 + n
  float lrow = 0.f;     // row sum at mcur scale (replicated across q4)
  float acarry = 1.0f;  // rescale factor decided at end of previous iter

  for (int jt = 0; jt < 64; ++jt) {
    const int j0 = jt * 64;
    const unsigned short* kb = kbuf[jt & 1];

    // prefetch V[jt] into registers (always the 8 NEWEST vmem ops)
    i32x4 vreg[8];
#pragma unroll
    for (int ct = 0; ct < 4; ++ct) {
      const unsigned short* vp = vb + (size_t)(w * 64 + ct * 16 + n) * NPOS + j0 + q4 * 8;
      vreg[ct * 2]     = *reinterpret_cast<const i32x4*>(vp);
      vreg[ct * 2 + 1] = *reinterpret_cast<const i32x4*>(vp + 32);
    }

    WAIT_VM8();     // drain everything older than V[jt] => K[jt] DMA complete
    BAR_RAW();      // all waves' K[jt] in LDS; pbuf/stat free (readers done pre-barrier)

    // S^T = K * Q: A = K (LDS, swizzled), B = Q regs.
    // D: lane holds S^T[j = nt*16 + q4*4 + r][i = n]
    f32x4 sacc[4];
    __builtin_amdgcn_s_setprio(1);
#pragma unroll
    for (int nt = 0; nt < 4; ++nt) {
      const unsigned short* krow = kb + (nt * 16 + n) * 256;
      sacc[nt] = {0.f, 0.f, 0.f, 0.f};
#pragma unroll
      for (int kk = 0; kk < 8; ++kk) {
        const int gp = (kk * 4 + q4) ^ nsw;
        bf16x8 bfr = ld_bf8(krow + gp * 8);
        sacc[nt] = __builtin_amdgcn_mfma_f32_16x16x32_bf16(bfr, afr[kk], sacc[nt], 0, 0, 0);
      }
    }
    __builtin_amdgcn_s_setprio(0);

    // local max tree (kept for the update check; off the exp critical path)
    float tml;
    {
      float a0 = fmaxf(fmaxf(sacc[0][0], sacc[0][1]), fmaxf(sacc[0][2], sacc[0][3]));
      float a1 = fmaxf(fmaxf(sacc[1][0], sacc[1][1]), fmaxf(sacc[1][2], sacc[1][3]));
      float a2 = fmaxf(fmaxf(sacc[2][0], sacc[2][1]), fmaxf(sacc[2][2], sacc[2][3]));
      float a3 = fmaxf(fmaxf(sacc[3][0], sacc[3][1]), fmaxf(sacc[3][2], sacc[3][3]));
      tml = fmaxf(fmaxf(a0, a1), fmaxf(a2, a3));
    }

    // P = exp2(S - mcur), lagging scale: starts immediately, no max wait
    float s = 0.f;
#pragma unroll
    for (int nt = 0; nt < 4; ++nt) {
#pragma unroll
      for (int r = 0; r < 4; ++r) {
        const float p = fexp2(sacc[nt][r] - mcur);
        sacc[nt][r] = p;
        s += p;
      }
    }

    // P -> pbuf row i = w*16+n: j pairs packed, 4 x ds_write_b64.
    // u16 slot j, granule = j/8, phys = granule ^ (row&7) = granule ^ nsw.
    {
      const int rowb = (w * 16 + n) * 64;
#pragma unroll
      for (int nt = 0; nt < 4; ++nt) {
        const unsigned lo = cvtpk(sacc[nt][0], sacc[nt][1]);
        const unsigned hi = cvtpk(sacc[nt][2], sacc[nt][3]);
        const int pg = (2 * nt + (q4 >> 1)) ^ nsw;
        i32x2 dv = { (int)lo, (int)hi };
        *reinterpret_cast<i32x2*>(&pbuf[rowb + pg * 8 + (q4 & 1) * 4]) = dv;
      }
    }
    if (q4 == 0) stat_lds[w * 16 + n] = acarry;   // rescale decided last iter

    // reductions off critical path
    s += __shfl_xor(s, 16);
    s += __shfl_xor(s, 32);
    lrow += s;
    float tm = fmaxf(tml, __shfl_xor(tml, 16));
    tm = fmaxf(tm, __shfl_xor(tm, 32));

    // prefetch K[jt+1] DMA into other buffer (UNCONDITIONAL, wrapped: keeps
    // compiler's V-use wait at vmcnt(8) instead of vmcnt(0))
    {
      const int j0n = ((jt + 1) & 63) * 64;
      unsigned short* bufn = kbuf[(jt + 1) & 1];
#pragma unroll
      for (int it = 0; it < 8; ++it) {
        const int t = w * 8 + it;
        const int j = 2 * t + (l >> 5);
        const int gp = l & 31;
        const int g  = gp ^ (j & 7);
        const unsigned short* src = kTb + (size_t)(j0n + j) * CCH + g * 8;
        unsigned short* dst = &bufn[t * 512];
        __builtin_amdgcn_global_load_lds((GAS*)src, (LAS*)dst, 16, 0, 0);
      }
    }

    WAIT_LGKM0();   // my P/alpha writes landed
    BAR_RAW();      // P + alpha visible to all; K' DMA still in flight

    // rescale O by alpha[i] — skipped when no wave updated last iter
    {
      const float al0 = stat_lds[n];
      const float al1 = stat_lds[16 + n];
      const float al2 = stat_lds[32 + n];
      const float al3 = stat_lds[48 + n];
      if (al0 + al1 + al2 + al3 != 4.0f) {
        const float als[4] = { al0, al1, al2, al3 };
#pragma unroll
        for (int it = 0; it < 4; ++it) {
          const float al = als[it];
#pragma unroll
          for (int ct = 0; ct < 4; ++ct) {
            f32x4& o = O[ct * 4 + it];
            o[0] *= al; o[1] *= al; o[2] *= al; o[3] *= al;
          }
        }
      }
    }

    // PV: V from registers, P from swizzled LDS
    bf16x8 pf[8];
#pragma unroll
    for (int it = 0; it < 4; ++it) {
      const int rowb = (it * 16 + n) * 64;
      pf[it * 2 + 0] = ld_bf8(&pbuf[rowb + ((q4 ^ nsw) << 3)]);
      pf[it * 2 + 1] = ld_bf8(&pbuf[rowb + (((4 + q4) ^ nsw) << 3)]);
    }
    __builtin_amdgcn_s_setprio(1);
#pragma unroll
    for (int ct = 0; ct < 4; ++ct) {
      bf16x8 vf0 = __builtin_bit_cast(bf16x8, vreg[ct * 2]);
      bf16x8 vf1 = __builtin_bit_cast(bf16x8, vreg[ct * 2 + 1]);
#pragma unroll
      for (int it = 0; it < 4; ++it) {
        O[ct * 4 + it] = __builtin_amdgcn_mfma_f32_16x16x32_bf16(vf0, pf[it * 2 + 0], O[ct * 4 + it], 0, 0, 0);
        O[ct * 4 + it] = __builtin_amdgcn_mfma_f32_16x16x32_bf16(vf1, pf[it * 2 + 1], O[ct * 4 + it], 0, 0, 0);
      }
    }
    __builtin_amdgcn_s_setprio(0);

    // deferred max update (rare): threshold 8 bounds P <= 2^8 between updates
    const int upd = tm > mcur + 8.f;
    if (__any(upd)) {
      const float mn = upd ? tm : mcur;
      const float al = fexp2(mcur - mn);
      mcur = mn;
      lrow *= al;
      acarry = al;
    } else {
      acarry = 1.0f;
    }
  }

  // epilogue: out = x + g*(acarry*O)/lrow — acarry folds in the final
  // iteration's pending O-rescale.
  __syncthreads();
  if (q4 == 0) stat_lds[w * 16 + n] = acarry / lrow;
  __syncthreads();

  const float g = gamma[0];
#pragma unroll
  for (int it = 0; it < 4; ++it) {
    const float sc = g * stat_lds[it * 16 + n];
    const int ipos = i0 + it * 16 + n;
#pragma unroll
    for (int ct = 0; ct < 4; ++ct) {
#pragma unroll
      for (int r = 0; r < 4; ++r) {
        const int c = w * 64 + ct * 16 + q4 * 4 + r;
        const size_t idx = ((size_t)(b * CCH + c)) * NPOS + ipos;
        out[idx] = x[idx] + sc * O[ct * 4 + it][r];
      }
    }
  }
}

// ---------------------------------------------------------------- launch
extern "C" void kernel_launch(void* const* d_in, const int* in_sizes, int n_in,
                              void* d_out, int out_size, void* d_ws, size_t ws_size,
                              hipStream_t stream)
{
  const float* x     = (const float*)d_in[0];
  const float* Wq    = (const float*)d_in[1];
  const float* bq    = (const float*)d_in[2];
  const float* Wk    = (const float*)d_in[3];
  const float* bk    = (const float*)d_in[4];
  const float* Wv    = (const float*)d_in[5];
  const float* bv    = (const float*)d_in[6];
  const float* gamma = (const float*)d_in[7];
  float* out = (float*)d_out;

  unsigned short* ws   = (unsigned short*)d_ws;
  unsigned short* Wall = ws;                                  // 3 x 65536 bf16
  unsigned short* qT   = ws + 196608;                         // (B,N,C) bf16, pre-scaled log2e
  unsigned short* kT   = qT + (size_t)BATCH * NPOS * CCH;     // (B,N,C) bf16
  unsigned short* vG   = kT + (size_t)BATCH * NPOS * CCH;     // (B,C,N) bf16

  cvt_kernel<<<768, 256, 0, stream>>>(Wq, Wk, Wv, Wall);
  qkv_kernel<<<dim3(8, 64), 256, 0, stream>>>(x, Wall, bq, bk, bv, qT, kT, vG);
  attn_kernel<<<dim3(8, 64), 256, 0, stream>>>(qT, kT, vG, x, gamma, out);
}

// Round 12
// 289.995 us; speedup vs baseline: 1.2091x; 1.0070x over previous
//
#include <hip/hip_runtime.h>

#define BATCH 8
#define CCH 256
#define NPOS 4096
#define LOG2E 1.4426950408889634f

typedef __bf16 bf16x8 __attribute__((ext_vector_type(8)));
typedef float f32x4 __attribute__((ext_vector_type(4)));
typedef int i32x4 __attribute__((ext_vector_type(4)));
typedef int i32x2 __attribute__((ext_vector_type(2)));

typedef const __attribute__((address_space(1))) void GAS;
typedef __attribute__((address_space(3))) void LAS;

#define CFENCE() __asm__ volatile("" ::: "memory")
// vmcnt(8), lgkmcnt no-wait(15), expcnt no-wait(7): (15<<8)|(7<<4)|8
#define WAIT_VM8()  do { CFENCE(); __builtin_amdgcn_s_waitcnt(0x0F78); CFENCE(); } while (0)
// lgkmcnt(0), vmcnt no-wait(63: low4=15,hi2=3), expcnt no-wait
#define WAIT_LGKM0() do { CFENCE(); __builtin_amdgcn_s_waitcnt(0xC07F); CFENCE(); } while (0)
#define BAR_RAW() do { CFENCE(); __builtin_amdgcn_s_barrier(); CFENCE(); } while (0)

__device__ __forceinline__ unsigned short f2bf(float f) {
  unsigned u = __builtin_bit_cast(unsigned, f);
  u += 0x7fffu + ((u >> 16) & 1u);
  return (unsigned short)(u >> 16);
}

__device__ __forceinline__ bf16x8 ld_bf8(const unsigned short* p) {
  i32x4 t = *reinterpret_cast<const i32x4*>(p);
  return __builtin_bit_cast(bf16x8, t);
}

__device__ __forceinline__ float fexp2(float x) {
#if __has_builtin(__builtin_amdgcn_exp2f)
  return __builtin_amdgcn_exp2f(x);
#else
  return __builtin_exp2f(x);
#endif
}

// packed f32x2 -> bf16x2 (RNE), one VALU op
__device__ __forceinline__ unsigned cvtpk(float lo, float hi) {
  unsigned r;
  asm("v_cvt_pk_bf16_f32 %0, %1, %2" : "=v"(r) : "v"(lo), "v"(hi));
  return r;
}

// ---------------------------------------------------------------- kernel 1
__global__ void cvt_kernel(const float* __restrict__ Wq,
                           const float* __restrict__ Wk,
                           const float* __restrict__ Wv,
                           unsigned short* __restrict__ dst)
{
  const int idx = blockIdx.x * 256 + threadIdx.x;   // 0..196607
  const float* src = (idx < 65536) ? Wq : ((idx < 131072) ? Wk : Wv);
  dst[idx] = f2bf(src[idx & 65535]);
}

// ---------------------------------------------------------------- kernel 2
// 12 fully-unrolled phases; r11's W-prefetch + tbuf double-buffer kept.
// NEW: xT layout [64][256] with kbuf-style XOR-granule swizzle
// (phys granule = (col>>3) ^ (row&7)) — the old 264-stride layout put the
// MFMA B-frag ds_read_b128 at 8-way bank conflict (bank = 4(n+q4) mod 32);
// swizzled reads mirror attn's proven K-read pattern. LDS 51.2 KB.
__global__ __launch_bounds__(256, 3)
void qkv_kernel(const float* __restrict__ x,
                const unsigned short* __restrict__ Wall,
                const float* __restrict__ bq,
                const float* __restrict__ bk,
                const float* __restrict__ bv,
                unsigned short* __restrict__ qT,
                unsigned short* __restrict__ kT,
                unsigned short* __restrict__ vG)
{
  __shared__ __align__(16) unsigned short xT[64 * 256];      // 32768 B, swizzled
  __shared__ __align__(16) unsigned short tbuf[2][64 * 72];  // 18432 B

  const int b   = blockIdx.x;
  const int i0  = blockIdx.y * 64;
  const int tid = threadIdx.x;
  const int w   = tid >> 6;
  const int l   = tid & 63;
  const int n   = l & 15;
  const int q4  = l >> 4;

  // stage x tile, coalesced reads; swizzled scalar writes:
  // row = pos-local, col = channel; phys granule = (col>>3) ^ (row&7)
  {
    const int li = tid & 15;
    const int cg = tid >> 4;
#pragma unroll
    for (int it = 0; it < 16; ++it) {
      const int c = it * 16 + cg;
      const int g = it * 2 + (cg >> 3);
      const int co = cg & 7;
      f32x4 f = *reinterpret_cast<const f32x4*>(x + ((size_t)b * CCH + c) * NPOS + i0 + li * 4);
#pragma unroll
      for (int e = 0; e < 4; ++e) {
        const int row = li * 4 + e;
        xT[row * 256 + ((g ^ (row & 7)) << 3) + co] = f2bf(f[e]);
      }
    }
  }
  __syncthreads();

  const size_t qbase = (size_t)b * NPOS * CCH;
  const float* const biases[3] = { bq, bk, bv };
  const int nsw = n & 7;

  // prefetch phase 0 W strip + bias
  bf16x8 wcur[8];
  float bcur[4];
  {
    const unsigned short* Wp = Wall + (size_t)(w * 16 + n) * CCH + q4 * 8;
#pragma unroll
    for (int kk = 0; kk < 8; ++kk) wcur[kk] = ld_bf8(Wp + kk * 32);
#pragma unroll
    for (int r = 0; r < 4; ++r) bcur[r] = bq[w * 16 + q4 * 4 + r];
  }

#pragma unroll
  for (int ph = 0; ph < 12; ++ph) {
    const int s = ph >> 2, op = ph & 3, obase = op * 64;

    // prefetch next phase's W + bias (covered by this phase's MFMAs)
    bf16x8 wnxt[8];
    float bnxt[4];
    if (ph < 11) {
      const int s2 = (ph + 1) >> 2, op2 = (ph + 1) & 3;
      const unsigned short* Wp =
          Wall + s2 * 65536 + (size_t)(op2 * 64 + w * 16 + n) * CCH + q4 * 8;
#pragma unroll
      for (int kk = 0; kk < 8; ++kk) wnxt[kk] = ld_bf8(Wp + kk * 32);
      const float* b2 = biases[s2];
#pragma unroll
      for (int r = 0; r < 4; ++r) bnxt[r] = b2[op2 * 64 + w * 16 + q4 * 4 + r];
    }

    f32x4 acc[4];
#pragma unroll
    for (int pt = 0; pt < 4; ++pt) {
      acc[pt] = {0.f, 0.f, 0.f, 0.f};
      const unsigned short* xrow = &xT[(pt * 16 + n) * 256];
#pragma unroll
      for (int kk = 0; kk < 8; ++kk) {
        const int gp = (kk * 4 + q4) ^ nsw;
        bf16x8 bfr = ld_bf8(xrow + gp * 8);
        acc[pt] = __builtin_amdgcn_mfma_f32_16x16x32_bf16(wcur[kk], bfr, acc[pt], 0, 0, 0);
      }
    }

    // write tbuf[ph&1]  (D layout: col = lane&15 = pos, row = o-local)
    unsigned short* tb = tbuf[ph & 1];
    if (s < 2) {
      const float sc = (s == 0) ? LOG2E : 1.0f;
#pragma unroll
      for (int pt = 0; pt < 4; ++pt)
#pragma unroll
        for (int r = 0; r < 4; ++r)
          tb[(pt * 16 + n) * 72 + w * 16 + q4 * 4 + r] = f2bf((acc[pt][r] + bcur[r]) * sc);
    } else {
#pragma unroll
      for (int pt = 0; pt < 4; ++pt)
#pragma unroll
        for (int r = 0; r < 4; ++r)
          tb[(w * 16 + q4 * 4 + r) * 72 + pt * 16 + n] = f2bf(acc[pt][r] + bcur[r]);
    }
    __syncthreads();   // tb visible; previous parity's readers also done

    // stores from tbuf[ph&1] (overlap next phase's prefetch+MFMAs)
    if (s < 2) {
      unsigned short* dst = (s == 0 ? qT : kT) + qbase;
#pragma unroll
      for (int it2 = 0; it2 < 2; ++it2) {
        const int idx = it2 * 256 + tid;
        const int pos = idx >> 3, ow = (idx & 7) * 8;
        i32x4 d = *reinterpret_cast<const i32x4*>(&tb[pos * 72 + ow]);
        *reinterpret_cast<i32x4*>(&dst[(size_t)(i0 + pos) * CCH + obase + ow]) = d;
      }
    } else {
#pragma unroll
      for (int it2 = 0; it2 < 2; ++it2) {
        const int idx = it2 * 256 + tid;
        const int o = idx >> 3, pw2 = (idx & 7) * 8;
        i32x4 d = *reinterpret_cast<const i32x4*>(&tb[o * 72 + pw2]);
        *reinterpret_cast<i32x4*>(&vG[qbase + (size_t)(obase + o) * NPOS + i0 + pw2]) = d;
      }
    }

    if (ph < 11) {
#pragma unroll
      for (int kk = 0; kk < 8; ++kk) wcur[kk] = wnxt[kk];
#pragma unroll
      for (int r = 0; r < 4; ++r) bcur[r] = bnxt[r];
    }
  }
}

// ---------------------------------------------------------------- kernel 3
// Flash attention — byte-identical to the r9/r11 kernel (verified ~207 µs,
// absmax 0.0156): S^T operand swap, lagging-max softmax (epilogue folds the
// final pending rescale), rescale-skip, setprio, swizzled K/P LDS, K DMA
// double-buffer, V per-lane global b128.
__global__ __launch_bounds__(256, 2)
void attn_kernel(const unsigned short* __restrict__ qT,
                 const unsigned short* __restrict__ kT,
                 const unsigned short* __restrict__ vG,
                 const float* __restrict__ x,
                 const float* __restrict__ gamma,
                 float* __restrict__ out)
{
  __shared__ __align__(16) unsigned short kbuf[2][64 * 256];  // 2 x 32768 B, swizzled
  __shared__ __align__(16) unsigned short pbuf[64 * 64];      //  8192 B, swizzled
  __shared__ float stat_lds[64];

  const int b   = blockIdx.x;
  const int i0  = blockIdx.y * 64;
  const int tid = threadIdx.x;
  const int w   = tid >> 6;
  const int l   = tid & 63;
  const int n   = l & 15;
  const int q4  = l >> 4;
  const int nsw = n & 7;

  const unsigned short* qTb = qT + (size_t)b * NPOS * CCH;
  const unsigned short* kTb = kT + (size_t)b * NPOS * CCH;
  const unsigned short* vb  = vG + (size_t)b * NPOS * CCH;

  // Q fragments register-resident (pre-scaled by log2e). Used as B operand:
  // lane holds Q[i = i0 + w*16 + n][ch = kk*32 + q4*8 + e]
  bf16x8 afr[8];
  {
    const unsigned short* qrow = qTb + (size_t)(i0 + w * 16 + n) * CCH + q4 * 8;
#pragma unroll
    for (int kk = 0; kk < 8; ++kk)
      afr[kk] = ld_bf8(qrow + kk * 32);
  }

  // stage K[0]: wave issues 8 DMA loads, instruction t covers local rows 2t,2t+1.
  // LDS granule (j,gp) holds logical granule g = gp ^ (j&7)  (bank-spread swizzle).
  {
#pragma unroll
    for (int it = 0; it < 8; ++it) {
      const int t = w * 8 + it;
      const int j = 2 * t + (l >> 5);
      const int gp = l & 31;
      const int g  = gp ^ (j & 7);
      const unsigned short* src = kTb + (size_t)j * CCH + g * 8;
      unsigned short* dst = &kbuf[0][t * 512];    // wave-uniform base
      __builtin_amdgcn_global_load_lds((GAS*)src, (LAS*)dst, 16, 0, 0);
    }
  }

  f32x4 O[16];   // [ct*4+it]: c in [w*64+ct*16,+16), i in [it*16,+16)
#pragma unroll
  for (int t = 0; t < 16; ++t) O[t] = {0.f, 0.f, 0.f, 0.f};
  float mcur = 64.f;    // lagging exp2-domain max for i = i0 + w*16 + n
  float lrow = 0.f;     // row sum at mcur scale (replicated across q4)
  float acarry = 1.0f;  // rescale factor decided at end of previous iter

  for (int jt = 0; jt < 64; ++jt) {
    const int j0 = jt * 64;
    const unsigned short* kb = kbuf[jt & 1];

    // prefetch V[jt] into registers (always the 8 NEWEST vmem ops)
    i32x4 vreg[8];
#pragma unroll
    for (int ct = 0; ct < 4; ++ct) {
      const unsigned short* vp = vb + (size_t)(w * 64 + ct * 16 + n) * NPOS + j0 + q4 * 8;
      vreg[ct * 2]     = *reinterpret_cast<const i32x4*>(vp);
      vreg[ct * 2 + 1] = *reinterpret_cast<const i32x4*>(vp + 32);
    }

    WAIT_VM8();     // drain everything older than V[jt] => K[jt] DMA complete
    BAR_RAW();      // all waves' K[jt] in LDS; pbuf/stat free (readers done pre-barrier)

    // S^T = K * Q: A = K (LDS, swizzled), B = Q regs.
    // D: lane holds S^T[j = nt*16 + q4*4 + r][i = n]
    f32x4 sacc[4];
    __builtin_amdgcn_s_setprio(1);
#pragma unroll
    for (int nt = 0; nt < 4; ++nt) {
      const unsigned short* krow = kb + (nt * 16 + n) * 256;
      sacc[nt] = {0.f, 0.f, 0.f, 0.f};
#pragma unroll
      for (int kk = 0; kk < 8; ++kk) {
        const int gp = (kk * 4 + q4) ^ nsw;
        bf16x8 bfr = ld_bf8(krow + gp * 8);
        sacc[nt] = __builtin_amdgcn_mfma_f32_16x16x32_bf16(bfr, afr[kk], sacc[nt], 0, 0, 0);
      }
    }
    __builtin_amdgcn_s_setprio(0);

    // local max tree (kept for the update check; off the exp critical path)
    float tml;
    {
      float a0 = fmaxf(fmaxf(sacc[0][0], sacc[0][1]), fmaxf(sacc[0][2], sacc[0][3]));
      float a1 = fmaxf(fmaxf(sacc[1][0], sacc[1][1]), fmaxf(sacc[1][2], sacc[1][3]));
      float a2 = fmaxf(fmaxf(sacc[2][0], sacc[2][1]), fmaxf(sacc[2][2], sacc[2][3]));
      float a3 = fmaxf(fmaxf(sacc[3][0], sacc[3][1]), fmaxf(sacc[3][2], sacc[3][3]));
      tml = fmaxf(fmaxf(a0, a1), fmaxf(a2, a3));
    }

    // P = exp2(S - mcur), lagging scale: starts immediately, no max wait
    float s = 0.f;
#pragma unroll
    for (int nt = 0; nt < 4; ++nt) {
#pragma unroll
      for (int r = 0; r < 4; ++r) {
        const float p = fexp2(sacc[nt][r] - mcur);
        sacc[nt][r] = p;
        s += p;
      }
    }

    // P -> pbuf row i = w*16+n: j pairs packed, 4 x ds_write_b64.
    // u16 slot j, granule = j/8, phys = granule ^ (row&7) = granule ^ nsw.
    {
      const int rowb = (w * 16 + n) * 64;
#pragma unroll
      for (int nt = 0; nt < 4; ++nt) {
        const unsigned lo = cvtpk(sacc[nt][0], sacc[nt][1]);
        const unsigned hi = cvtpk(sacc[nt][2], sacc[nt][3]);
        const int pg = (2 * nt + (q4 >> 1)) ^ nsw;
        i32x2 dv = { (int)lo, (int)hi };
        *reinterpret_cast<i32x2*>(&pbuf[rowb + pg * 8 + (q4 & 1) * 4]) = dv;
      }
    }
    if (q4 == 0) stat_lds[w * 16 + n] = acarry;   // rescale decided last iter

    // reductions off critical path
    s += __shfl_xor(s, 16);
    s += __shfl_xor(s, 32);
    lrow += s;
    float tm = fmaxf(tml, __shfl_xor(tml, 16));
    tm = fmaxf(tm, __shfl_xor(tm, 32));

    // prefetch K[jt+1] DMA into other buffer (UNCONDITIONAL, wrapped: keeps
    // compiler's V-use wait at vmcnt(8) instead of vmcnt(0))
    {
      const int j0n = ((jt + 1) & 63) * 64;
      unsigned short* bufn = kbuf[(jt + 1) & 1];
#pragma unroll
      for (int it = 0; it < 8; ++it) {
        const int t = w * 8 + it;
        const int j = 2 * t + (l >> 5);
        const int gp = l & 31;
        const int g  = gp ^ (j & 7);
        const unsigned short* src = kTb + (size_t)(j0n + j) * CCH + g * 8;
        unsigned short* dst = &bufn[t * 512];
        __builtin_amdgcn_global_load_lds((GAS*)src, (LAS*)dst, 16, 0, 0);
      }
    }

    WAIT_LGKM0();   // my P/alpha writes landed
    BAR_RAW();      // P + alpha visible to all; K' DMA still in flight

    // rescale O by alpha[i] — skipped when no wave updated last iter
    {
      const float al0 = stat_lds[n];
      const float al1 = stat_lds[16 + n];
      const float al2 = stat_lds[32 + n];
      const float al3 = stat_lds[48 + n];
      if (al0 + al1 + al2 + al3 != 4.0f) {
        const float als[4] = { al0, al1, al2, al3 };
#pragma unroll
        for (int it = 0; it < 4; ++it) {
          const float al = als[it];
#pragma unroll
          for (int ct = 0; ct < 4; ++ct) {
            f32x4& o = O[ct * 4 + it];
            o[0] *= al; o[1] *= al; o[2] *= al; o[3] *= al;
          }
        }
      }
    }

    // PV: V from registers, P from swizzled LDS
    bf16x8 pf[8];
#pragma unroll
    for (int it = 0; it < 4; ++it) {
      const int rowb = (it * 16 + n) * 64;
      pf[it * 2 + 0] = ld_bf8(&pbuf[rowb + ((q4 ^ nsw) << 3)]);
      pf[it * 2 + 1] = ld_bf8(&pbuf[rowb + (((4 + q4) ^ nsw) << 3)]);
    }
    __builtin_amdgcn_s_setprio(1);
#pragma unroll
    for (int ct = 0; ct < 4; ++ct) {
      bf16x8 vf0 = __builtin_bit_cast(bf16x8, vreg[ct * 2]);
      bf16x8 vf1 = __builtin_bit_cast(bf16x8, vreg[ct * 2 + 1]);
#pragma unroll
      for (int it = 0; it < 4; ++it) {
        O[ct * 4 + it] = __builtin_amdgcn_mfma_f32_16x16x32_bf16(vf0, pf[it * 2 + 0], O[ct * 4 + it], 0, 0, 0);
        O[ct * 4 + it] = __builtin_amdgcn_mfma_f32_16x16x32_bf16(vf1, pf[it * 2 + 1], O[ct * 4 + it], 0, 0, 0);
      }
    }
    __builtin_amdgcn_s_setprio(0);

    // deferred max update (rare): threshold 8 bounds P <= 2^8 between updates
    const int upd = tm > mcur + 8.f;
    if (__any(upd)) {
      const float mn = upd ? tm : mcur;
      const float al = fexp2(mcur - mn);
      mcur = mn;
      lrow *= al;
      acarry = al;
    } else {
      acarry = 1.0f;
    }
  }

  // epilogue: out = x + g*(acarry*O)/lrow — acarry folds in the final
  // iteration's pending O-rescale.
  __syncthreads();
  if (q4 == 0) stat_lds[w * 16 + n] = acarry / lrow;
  __syncthreads();

  const float g = gamma[0];
#pragma unroll
  for (int it = 0; it < 4; ++it) {
    const float sc = g * stat_lds[it * 16 + n];
    const int ipos = i0 + it * 16 + n;
#pragma unroll
    for (int ct = 0; ct < 4; ++ct) {
#pragma unroll
      for (int r = 0; r < 4; ++r) {
        const int c = w * 64 + ct * 16 + q4 * 4 + r;
        const size_t idx = ((size_t)(b * CCH + c)) * NPOS + ipos;
        out[idx] = x[idx] + sc * O[ct * 4 + it][r];
      }
    }
  }
}

// ---------------------------------------------------------------- launch
extern "C" void kernel_launch(void* const* d_in, const int* in_sizes, int n_in,
                              void* d_out, int out_size, void* d_ws, size_t ws_size,
                              hipStream_t stream)
{
  const float* x     = (const float*)d_in[0];
  const float* Wq    = (const float*)d_in[1];
  const float* bq    = (const float*)d_in[2];
  const float* Wk    = (const float*)d_in[3];
  const float* bk    = (const float*)d_in[4];
  const float* Wv    = (const float*)d_in[5];
  const float* bv    = (const float*)d_in[6];
  const float* gamma = (const float*)d_in[7];
  float* out = (float*)d_out;

  unsigned short* ws   = (unsigned short*)d_ws;
  unsigned short* Wall = ws;                                  // 3 x 65536 bf16
  unsigned short* qT   = ws + 196608;                         // (B,N,C) bf16, pre-scaled log2e
  unsigned short* kT   = qT + (size_t)BATCH * NPOS * CCH;     // (B,N,C) bf16
  unsigned short* vG   = kT + (size_t)BATCH * NPOS * CCH;     // (B,C,N) bf16

  cvt_kernel<<<768, 256, 0, stream>>>(Wq, Wk, Wv, Wall);
  qkv_kernel<<<dim3(8, 64), 256, 0, stream>>>(x, Wall, bq, bk, bv, qT, kT, vG);
  attn_kernel<<<dim3(8, 64), 256, 0, stream>>>(qT, kT, vG, x, gamma, out);
}